// Round 1
// baseline (261.690 us; speedup 1.0000x reference)
//
#include <hip/hip_runtime.h>
#include <math.h>

#define HDIM 512
#define ADIM 512
#define BATCH 32
#define TDIM 32
#define KDIM 196

// ---------------------------------------------------------------------------
// fast tanh: tanh(x) = 1 - 2/(exp(2x)+1). Saturates correctly at +/-inf.
// ---------------------------------------------------------------------------
__device__ __forceinline__ float tanh_fast(float x) {
    float e = __expf(2.0f * x);               // v_exp_f32 path
    return 1.0f - 2.0f * __builtin_amdgcn_rcpf(e + 1.0f);
}

// ---------------------------------------------------------------------------
// fp32 tiled GEMM: C[M x 512] = A[M x 512] @ B[512 x 512], all row-major.
// BM=BN=64, BK=16, 256 threads, 4x4 micro-tile per thread.
// M must be a multiple of 64 (6272 and 1024 both are).
// ---------------------------------------------------------------------------
__global__ __launch_bounds__(256) void gemm_f32(const float* __restrict__ Amat,
                                                const float* __restrict__ Bmat,
                                                float* __restrict__ Cmat) {
    __shared__ float As[16][64 + 4];   // As[k][m], padded to kill write conflicts
    __shared__ float Bs[16][64];       // Bs[k][n]

    const int tid = threadIdx.x;
    const int tx = tid & 15;           // 0..15 -> n micro
    const int ty = tid >> 4;           // 0..15 -> m micro
    const int row0 = blockIdx.x * 64;
    const int col0 = blockIdx.y * 64;

    float acc[4][4] = {};

    for (int k0 = 0; k0 < HDIM; k0 += 16) {
        // ---- stage A tile (64x16) : 4 elems/thread
        #pragma unroll
        for (int i = 0; i < 4; ++i) {
            int idx = tid + i * 256;
            int m = idx >> 4;          // /16
            int k = idx & 15;
            As[k][m] = Amat[(size_t)(row0 + m) * HDIM + k0 + k];
        }
        // ---- stage B tile (16x64) : 4 elems/thread, coalesced
        #pragma unroll
        for (int i = 0; i < 4; ++i) {
            int idx = tid + i * 256;
            int k = idx >> 6;          // /64
            int n = idx & 63;
            Bs[k][n] = Bmat[(size_t)(k0 + k) * ADIM + col0 + n];
        }
        __syncthreads();

        #pragma unroll
        for (int k = 0; k < 16; ++k) {
            float4 a4 = *(const float4*)&As[k][ty * 4];
            float4 b4 = *(const float4*)&Bs[k][tx * 4];
            float a[4] = {a4.x, a4.y, a4.z, a4.w};
            float b[4] = {b4.x, b4.y, b4.z, b4.w};
            #pragma unroll
            for (int i = 0; i < 4; ++i)
                #pragma unroll
                for (int j = 0; j < 4; ++j)
                    acc[i][j] += a[i] * b[j];
        }
        __syncthreads();
    }

    #pragma unroll
    for (int i = 0; i < 4; ++i) {
        size_t r = (size_t)(row0 + ty * 4 + i) * ADIM + col0 + tx * 4;
        #pragma unroll
        for (int j = 0; j < 4; ++j) Cmat[r + j] = acc[i][j];
    }
}

// ---------------------------------------------------------------------------
// z kernel: z_t[b,t,k] = sum_a wh[a] * tanh(cv[b,k,a] + cg[b,t,a])
// Also z_ext[b,t] = sum_a wh[a] * tanh(cs[b,t,a] + cg[b,t,a])   (ks==0 blocks)
// Grid: (B, T/8, 2 k-halves). Block: 512 threads = 8 waves; wave w owns t.
// cg row + wh live in registers (8 floats/lane); cv rows staged via LDS.
// ---------------------------------------------------------------------------
#define ZKC 16
__global__ __launch_bounds__(512) void z_kernel(const float* __restrict__ cv,
                                                const float* __restrict__ cg,
                                                const float* __restrict__ cs,
                                                const float* __restrict__ wh,
                                                float* __restrict__ z_t,
                                                float* __restrict__ z_ext) {
    __shared__ float cvs[ZKC][ADIM];   // 32 KB

    const int b    = blockIdx.x;
    const int tg   = blockIdx.y;
    const int ks   = blockIdx.z;
    const int wave = threadIdx.x >> 6;
    const int lane = threadIdx.x & 63;
    const int t    = tg * 8 + wave;

    const int k_begin = ks * 98;       // 196 split in two halves of 98

    // registers: cg row (lane holds a = 4*lane..+3 and 256+4*lane..+3), wh same
    const float4* cgv = (const float4*)(cg + ((size_t)b * TDIM + t) * ADIM);
    float4 cg0 = cgv[lane];
    float4 cg1 = cgv[64 + lane];
    const float4* whv = (const float4*)wh;
    float4 wh0 = whv[lane];
    float4 wh1 = whv[64 + lane];

    const float* cvb = cv + (size_t)b * KDIM * ADIM;

    for (int kc = 0; kc < 98; kc += ZKC) {
        int nk = min(ZKC, 98 - kc);
        __syncthreads();   // previous chunk fully consumed
        // stage nk cv rows (nk*128 float4, 512 threads)
        const float4* src = (const float4*)(cvb + (size_t)(k_begin + kc) * ADIM);
        for (int i = threadIdx.x; i < nk * 128; i += 512)
            ((float4*)cvs)[i] = src[i];
        __syncthreads();

        for (int kk = 0; kk < nk; ++kk) {
            float4 v0 = ((const float4*)&cvs[kk][0])[lane];
            float4 v1 = ((const float4*)&cvs[kk][0])[64 + lane];
            float p;
            p  = wh0.x * tanh_fast(v0.x + cg0.x);
            p += wh0.y * tanh_fast(v0.y + cg0.y);
            p += wh0.z * tanh_fast(v0.z + cg0.z);
            p += wh0.w * tanh_fast(v0.w + cg0.w);
            p += wh1.x * tanh_fast(v1.x + cg1.x);
            p += wh1.y * tanh_fast(v1.y + cg1.y);
            p += wh1.z * tanh_fast(v1.z + cg1.z);
            p += wh1.w * tanh_fast(v1.w + cg1.w);
            #pragma unroll
            for (int off = 32; off; off >>= 1) p += __shfl_xor(p, off, 64);
            if (lane == 0)
                z_t[((size_t)b * TDIM + t) * KDIM + k_begin + kc + kk] = p;
        }
    }

    if (ks == 0) {
        const float4* csv = (const float4*)(cs + ((size_t)b * TDIM + t) * ADIM);
        float4 s0 = csv[lane];
        float4 s1 = csv[64 + lane];
        float p;
        p  = wh0.x * tanh_fast(s0.x + cg0.x);
        p += wh0.y * tanh_fast(s0.y + cg0.y);
        p += wh0.z * tanh_fast(s0.z + cg0.z);
        p += wh0.w * tanh_fast(s0.w + cg0.w);
        p += wh1.x * tanh_fast(s1.x + cg1.x);
        p += wh1.y * tanh_fast(s1.y + cg1.y);
        p += wh1.z * tanh_fast(s1.z + cg1.z);
        p += wh1.w * tanh_fast(s1.w + cg1.w);
        #pragma unroll
        for (int off = 32; off; off >>= 1) p += __shfl_xor(p, off, 64);
        if (lane == 0) z_ext[b * TDIM + t] = p;
    }
}

// ---------------------------------------------------------------------------
// out kernel: per (b,t) block (256 thr): softmax over k, extended softmax
// with z_ext -> beta; c_t = alpha @ att_feats[b]; final blend + all outputs.
// ---------------------------------------------------------------------------
__global__ __launch_bounds__(256) void out_kernel(const float* __restrict__ z_t,
                                                  const float* __restrict__ z_ext,
                                                  const float* __restrict__ att,
                                                  const float* __restrict__ sen,
                                                  float* __restrict__ out_chat,
                                                  float* __restrict__ out_alpha,
                                                  float* __restrict__ out_beta) {
    __shared__ float alpha_s[KDIM];
    __shared__ float red[8];

    const int t = blockIdx.x;
    const int b = blockIdx.y;
    const int tid = threadIdx.x;

    const float* zrow = z_t + ((size_t)b * TDIM + t) * KDIM;
    float z = (tid < KDIM) ? zrow[tid] : -INFINITY;

    // block max
    float m = z;
    #pragma unroll
    for (int off = 32; off; off >>= 1) m = fmaxf(m, __shfl_xor(m, off, 64));
    if ((tid & 63) == 0) red[tid >> 6] = m;
    __syncthreads();
    m = fmaxf(fmaxf(red[0], red[1]), fmaxf(red[2], red[3]));

    float e = (tid < KDIM) ? __expf(z - m) : 0.0f;
    float s = e;
    #pragma unroll
    for (int off = 32; off; off >>= 1) s += __shfl_xor(s, off, 64);
    if ((tid & 63) == 0) red[4 + (tid >> 6)] = s;
    __syncthreads();
    float S = red[4] + red[5] + red[6] + red[7];

    float alpha = e / S;
    if (tid < KDIM) {
        alpha_s[tid] = alpha;
        out_alpha[((size_t)b * TDIM + t) * KDIM + tid] = alpha;
    }

    float se = z_ext[b * TDIM + t];
    float m2 = fmaxf(m, se);
    float eext = __expf(se - m2);
    float S2 = S * __expf(m - m2) + eext;
    float beta = eext / S2;
    if (tid == 0) out_beta[b * TDIM + t] = beta;
    __syncthreads();

    // c_t: thread covers h = tid and tid+256
    const float* attb = att + (size_t)b * KDIM * HDIM;
    float acc0 = 0.f, acc1 = 0.f;
    #pragma unroll 4
    for (int k = 0; k < KDIM; ++k) {
        float a = alpha_s[k];
        acc0 += a * attb[(size_t)k * HDIM + tid];
        acc1 += a * attb[(size_t)k * HDIM + tid + 256];
    }
    const float* srow = sen + ((size_t)b * TDIM + t) * HDIM;
    float om = 1.0f - beta;
    size_t o = ((size_t)b * TDIM + t) * HDIM;
    out_chat[o + tid]       = beta * srow[tid]       + om * acc0;
    out_chat[o + tid + 256] = beta * srow[tid + 256] + om * acc1;
}

// ---------------------------------------------------------------------------
extern "C" void kernel_launch(void* const* d_in, const int* in_sizes, int n_in,
                              void* d_out, int out_size, void* d_ws, size_t ws_size,
                              hipStream_t stream) {
    const float* att = (const float*)d_in[0];   // (32,196,512)
    const float* hid = (const float*)d_in[1];   // (32,32,512)
    const float* sen = (const float*)d_in[2];   // (32,32,512)
    const float* Wv  = (const float*)d_in[3];   // (512,512)
    const float* Wg  = (const float*)d_in[4];
    const float* Ws  = (const float*)d_in[5];
    const float* wh  = (const float*)d_in[6];   // (512,)

    float* out = (float*)d_out;
    float* out_chat  = out;                       // 32*32*512 = 524288
    float* out_alpha = out + 524288;              // 32*32*196 = 200704
    float* out_beta  = out + 524288 + 200704;     // 1024

    float* ws   = (float*)d_ws;
    float* cv   = ws;                             // 6272*512 = 3211264
    float* cg   = cv + 3211264;                   // 1024*512 = 524288
    float* cs   = cg + 524288;                    // 524288
    float* zt   = cs + 524288;                    // 200704
    float* zext = zt + 200704;                    // 1024

    dim3 blk(256);
    gemm_f32<<<dim3(98, 8), blk, 0, stream>>>(att, Wv, cv);   // 6272 rows
    gemm_f32<<<dim3(16, 8), blk, 0, stream>>>(hid, Wg, cg);   // 1024 rows
    gemm_f32<<<dim3(16, 8), blk, 0, stream>>>(sen, Ws, cs);   // 1024 rows

    z_kernel<<<dim3(BATCH, 4, 2), dim3(512), 0, stream>>>(cv, cg, cs, wh, zt, zext);

    out_kernel<<<dim3(TDIM, BATCH), dim3(256), 0, stream>>>(zt, zext, att, sen,
                                                            out_chat, out_alpha, out_beta);
}

// Round 2
// 165.987 us; speedup vs baseline: 1.5766x; 1.5766x over previous
//
#include <hip/hip_runtime.h>
#include <hip/hip_bf16.h>
#include <math.h>

#define HDIM 512
#define ADIM 512
#define BATCH 32
#define TDIM 32
#define KDIM 196
#define MROWS 8320            // 6272 (att) + 1024 (hid) + 1024 (sen)

typedef short short8 __attribute__((ext_vector_type(8)));
typedef float floatx4 __attribute__((ext_vector_type(4)));

// ---------------------------------------------------------------------------
// fast tanh: tanh(x) = 1 - 2/(exp(2x)+1). Saturates correctly at +/-inf.
// ---------------------------------------------------------------------------
__device__ __forceinline__ float tanh_fast(float x) {
    float e = __expf(2.0f * x);
    return 1.0f - 2.0f * __builtin_amdgcn_rcpf(e + 1.0f);
}

// ---------------------------------------------------------------------------
// async global->LDS 16B copy (global_load_lds_dwordx4)
// ---------------------------------------------------------------------------
__device__ __forceinline__ void gl_lds16(const __hip_bfloat16* g, __hip_bfloat16* l) {
    __builtin_amdgcn_global_load_lds(
        (const __attribute__((address_space(1))) unsigned int*)(const void*)g,
        (__attribute__((address_space(3))) unsigned int*)(void*)l, 16, 0, 0);
}

// ---------------------------------------------------------------------------
// convA: fp32 rows of att|hid|sen -> bf16 hi/lo arrays [8320 x 512]
// one thread per float4 (idx), 8320*128 = 1,064,960 float4s.
// ---------------------------------------------------------------------------
__global__ __launch_bounds__(256) void convA(const float* __restrict__ att,
                                             const float* __restrict__ hid,
                                             const float* __restrict__ sen,
                                             __hip_bfloat16* __restrict__ ahi,
                                             __hip_bfloat16* __restrict__ alo) {
    const int idx = blockIdx.x * 256 + threadIdx.x;
    const int row = idx >> 7;                  // 128 float4 per row
    float4 v;
    if (row < 6272)      v = ((const float4*)att)[idx];
    else if (row < 7296) v = ((const float4*)hid)[idx - 6272 * 128];
    else                 v = ((const float4*)sen)[idx - 7296 * 128];
    float x[4] = {v.x, v.y, v.z, v.w};
    union { __hip_bfloat16 b[4]; uint2 u; } H, L;
    #pragma unroll
    for (int i = 0; i < 4; ++i) {
        H.b[i] = __float2bfloat16(x[i]);
        L.b[i] = __float2bfloat16(x[i] - __bfloat162float(H.b[i]));
    }
    ((uint2*)ahi)[idx] = H.u;
    ((uint2*)alo)[idx] = L.u;
}

// ---------------------------------------------------------------------------
// convB: W[k][n] fp32 -> transposed bf16 hi/lo [3][n=512][k=512]
// 64x64 tile transpose through LDS. grid (8, 8, 3).
// ---------------------------------------------------------------------------
__global__ __launch_bounds__(256) void convB(const float* __restrict__ Wv,
                                             const float* __restrict__ Wg,
                                             const float* __restrict__ Ws,
                                             __hip_bfloat16* __restrict__ bthi,
                                             __hip_bfloat16* __restrict__ btlo) {
    __shared__ float tile[64][65];
    const int tid = threadIdx.x;
    const float* src = blockIdx.z == 0 ? Wv : (blockIdx.z == 1 ? Wg : Ws);
    const int k0 = blockIdx.x * 64, n0 = blockIdx.y * 64;
    #pragma unroll
    for (int i = 0; i < 16; ++i) {
        int k = (tid >> 6) * 16 + i;
        int n = tid & 63;
        tile[k][n] = src[(size_t)(k0 + k) * 512 + n0 + n];
    }
    __syncthreads();
    const size_t obase = (size_t)blockIdx.z * 262144;
    #pragma unroll
    for (int i = 0; i < 16; ++i) {
        int n = (tid >> 6) * 16 + i;
        int k = tid & 63;
        float x = tile[k][n];
        __hip_bfloat16 h = __float2bfloat16(x);
        __hip_bfloat16 l = __float2bfloat16(x - __bfloat162float(h));
        size_t o = obase + (size_t)(n0 + n) * 512 + k0 + k;
        bthi[o] = h;
        btlo[o] = l;
    }
}

// ---------------------------------------------------------------------------
// split-bf16 MFMA GEMM (bf16x3): C[8320 x 512] fp32 = A[8320 x 512] @ B[512 x 512]
// B given transposed (n-major). Per-row-segment weight select (Wv/Wg/Ws).
// Tile 64(M) x 128(N), BK=32. 256 threads = 4 waves in 2x2; each wave 32x64.
// grid (130, 4).
// ---------------------------------------------------------------------------
__global__ __launch_bounds__(256) void gemm_bf16x3(
        const __hip_bfloat16* __restrict__ Ahi, const __hip_bfloat16* __restrict__ Alo,
        const __hip_bfloat16* __restrict__ Bthi, const __hip_bfloat16* __restrict__ Btlo,
        float* __restrict__ C) {
    // LDS partitions (bf16 elems): sAhi [64][32] @0, sAlo @2048,
    //                              sBhi [128][32] @4096, sBlo @8192. 24 KB total.
    __shared__ __hip_bfloat16 smem[12288];

    const int tid  = threadIdx.x;
    const int lane = tid & 63;
    const int wave = tid >> 6;
    const int wm = wave >> 1;      // 0..1 -> m half
    const int wn = wave & 1;       // 0..1 -> n half
    const int row0 = blockIdx.x * 64;
    const int col0 = blockIdx.y * 128;
    const int seg = (row0 < 6272) ? 0 : ((row0 < 7296) ? 1 : 2);
    const __hip_bfloat16* Bh = Bthi + (size_t)seg * 262144;
    const __hip_bfloat16* Bl = Btlo + (size_t)seg * 262144;

    floatx4 acc[2][4];
    #pragma unroll
    for (int i = 0; i < 2; ++i)
        #pragma unroll
        for (int j = 0; j < 4; ++j)
            acc[i][j] = (floatx4){0.f, 0.f, 0.f, 0.f};

    const int kq8 = (lane >> 4) << 3;    // k-offset of this lane's fragment

    for (int k0 = 0; k0 < 512; k0 += 32) {
        // ---- stage: 1536 16B units, 6 per thread (wave-uniform branch) ----
        #pragma unroll
        for (int s = 0; s < 6; ++s) {
            int u = tid + (s << 8);
            __hip_bfloat16* ldst = smem + u * 8;
            const __hip_bfloat16* gsrc;
            if (u < 256)        gsrc = Ahi + (size_t)(row0 + (u >> 2)) * 512 + k0 + ((u & 3) << 3);
            else if (u < 512)   { int v = u - 256;  gsrc = Alo + (size_t)(row0 + (v >> 2)) * 512 + k0 + ((v & 3) << 3); }
            else if (u < 1024)  { int v = u - 512;  gsrc = Bh  + (size_t)(col0 + (v >> 2)) * 512 + k0 + ((v & 3) << 3); }
            else                { int v = u - 1024; gsrc = Bl  + (size_t)(col0 + (v >> 2)) * 512 + k0 + ((v & 3) << 3); }
            gl_lds16(gsrc, ldst);
        }
        asm volatile("s_waitcnt vmcnt(0)" ::: "memory");
        __syncthreads();

        // ---- fragments ----
        short8 a_hi[2], a_lo[2], b_hi[4], b_lo[4];
        #pragma unroll
        for (int i = 0; i < 2; ++i) {
            int m = wm * 32 + i * 16 + (lane & 15);
            a_hi[i] = *(const short8*)(smem + m * 32 + kq8);
            a_lo[i] = *(const short8*)(smem + 2048 + m * 32 + kq8);
        }
        #pragma unroll
        for (int j = 0; j < 4; ++j) {
            int n = wn * 64 + j * 16 + (lane & 15);
            b_hi[j] = *(const short8*)(smem + 4096 + n * 32 + kq8);
            b_lo[j] = *(const short8*)(smem + 8192 + n * 32 + kq8);
        }

        // ---- 3-product split MFMA ----
        #pragma unroll
        for (int i = 0; i < 2; ++i)
            #pragma unroll
            for (int j = 0; j < 4; ++j) {
                acc[i][j] = __builtin_amdgcn_mfma_f32_16x16x32_bf16(a_hi[i], b_hi[j], acc[i][j], 0, 0, 0);
                acc[i][j] = __builtin_amdgcn_mfma_f32_16x16x32_bf16(a_hi[i], b_lo[j], acc[i][j], 0, 0, 0);
                acc[i][j] = __builtin_amdgcn_mfma_f32_16x16x32_bf16(a_lo[i], b_hi[j], acc[i][j], 0, 0, 0);
            }
        __syncthreads();
    }

    // ---- epilogue: C/D layout col=lane&15, row=(lane>>4)*4+r ----
    #pragma unroll
    for (int i = 0; i < 2; ++i) {
        #pragma unroll
        for (int r = 0; r < 4; ++r) {
            int row = row0 + wm * 32 + i * 16 + ((lane >> 4) << 2) + r;
            float* cp = C + (size_t)row * 512 + col0 + wn * 64 + (lane & 15);
            #pragma unroll
            for (int j = 0; j < 4; ++j) cp[j * 16] = acc[i][j][r];
        }
    }
}

// ---------------------------------------------------------------------------
// fallback fp32 tiled GEMM (used only if workspace too small for bf16 path)
// ---------------------------------------------------------------------------
__global__ __launch_bounds__(256) void gemm_f32(const float* __restrict__ Amat,
                                                const float* __restrict__ Bmat,
                                                float* __restrict__ Cmat) {
    __shared__ float As[16][64 + 4];
    __shared__ float Bs[16][64];
    const int tid = threadIdx.x;
    const int tx = tid & 15;
    const int ty = tid >> 4;
    const int row0 = blockIdx.x * 64;
    const int col0 = blockIdx.y * 64;
    float acc[4][4] = {};
    for (int k0 = 0; k0 < HDIM; k0 += 16) {
        #pragma unroll
        for (int i = 0; i < 4; ++i) {
            int idx = tid + i * 256;
            As[idx & 15][idx >> 4] = Amat[(size_t)(row0 + (idx >> 4)) * HDIM + k0 + (idx & 15)];
        }
        #pragma unroll
        for (int i = 0; i < 4; ++i) {
            int idx = tid + i * 256;
            Bs[idx >> 6][idx & 63] = Bmat[(size_t)(k0 + (idx >> 6)) * ADIM + col0 + (idx & 63)];
        }
        __syncthreads();
        #pragma unroll
        for (int k = 0; k < 16; ++k) {
            float4 a4 = *(const float4*)&As[k][ty * 4];
            float4 b4 = *(const float4*)&Bs[k][tx * 4];
            float a[4] = {a4.x, a4.y, a4.z, a4.w};
            float b[4] = {b4.x, b4.y, b4.z, b4.w};
            #pragma unroll
            for (int i = 0; i < 4; ++i)
                #pragma unroll
                for (int j = 0; j < 4; ++j)
                    acc[i][j] += a[i] * b[j];
        }
        __syncthreads();
    }
    #pragma unroll
    for (int i = 0; i < 4; ++i) {
        size_t r = (size_t)(row0 + ty * 4 + i) * ADIM + col0 + tx * 4;
        #pragma unroll
        for (int j = 0; j < 4; ++j) Cmat[r + j] = acc[i][j];
    }
}

// ---------------------------------------------------------------------------
// z kernel: z_t[b,t,k] = sum_a wh[a]*tanh(cv[b,k,a]+cg[b,t,a]); z_ext similar.
// Grid (B, 4, 4 k-quarters of 49). Block 512 = 8 waves; wave owns one t.
// ---------------------------------------------------------------------------
#define ZKC 16
__global__ __launch_bounds__(512) void z_kernel(const float* __restrict__ cv,
                                                const float* __restrict__ cg,
                                                const float* __restrict__ cs,
                                                const float* __restrict__ wh,
                                                float* __restrict__ z_t,
                                                float* __restrict__ z_ext) {
    __shared__ float cvs[ZKC][ADIM];   // 32 KB

    const int b    = blockIdx.x;
    const int tg   = blockIdx.y;
    const int ks   = blockIdx.z;
    const int wave = threadIdx.x >> 6;
    const int lane = threadIdx.x & 63;
    const int t    = tg * 8 + wave;
    const int k_begin = ks * 49;       // 196 = 4 x 49

    const float4* cgv = (const float4*)(cg + ((size_t)b * TDIM + t) * ADIM);
    float4 cg0 = cgv[lane];
    float4 cg1 = cgv[64 + lane];
    const float4* whv = (const float4*)wh;
    float4 wh0 = whv[lane];
    float4 wh1 = whv[64 + lane];

    const float* cvb = cv + (size_t)b * KDIM * ADIM;

    for (int kc = 0; kc < 49; kc += ZKC) {
        int nk = min(ZKC, 49 - kc);
        __syncthreads();
        const float4* src = (const float4*)(cvb + (size_t)(k_begin + kc) * ADIM);
        for (int i = threadIdx.x; i < nk * 128; i += 512)
            ((float4*)cvs)[i] = src[i];
        __syncthreads();

        for (int kk = 0; kk < nk; ++kk) {
            float4 v0 = ((const float4*)&cvs[kk][0])[lane];
            float4 v1 = ((const float4*)&cvs[kk][0])[64 + lane];
            float p;
            p  = wh0.x * tanh_fast(v0.x + cg0.x);
            p += wh0.y * tanh_fast(v0.y + cg0.y);
            p += wh0.z * tanh_fast(v0.z + cg0.z);
            p += wh0.w * tanh_fast(v0.w + cg0.w);
            p += wh1.x * tanh_fast(v1.x + cg1.x);
            p += wh1.y * tanh_fast(v1.y + cg1.y);
            p += wh1.z * tanh_fast(v1.z + cg1.z);
            p += wh1.w * tanh_fast(v1.w + cg1.w);
            #pragma unroll
            for (int off = 32; off; off >>= 1) p += __shfl_xor(p, off, 64);
            if (lane == 0)
                z_t[((size_t)b * TDIM + t) * KDIM + k_begin + kc + kk] = p;
        }
    }

    if (ks == 0) {
        const float4* csv = (const float4*)(cs + ((size_t)b * TDIM + t) * ADIM);
        float4 s0 = csv[lane];
        float4 s1 = csv[64 + lane];
        float p;
        p  = wh0.x * tanh_fast(s0.x + cg0.x);
        p += wh0.y * tanh_fast(s0.y + cg0.y);
        p += wh0.z * tanh_fast(s0.z + cg0.z);
        p += wh0.w * tanh_fast(s0.w + cg0.w);
        p += wh1.x * tanh_fast(s1.x + cg1.x);
        p += wh1.y * tanh_fast(s1.y + cg1.y);
        p += wh1.z * tanh_fast(s1.z + cg1.z);
        p += wh1.w * tanh_fast(s1.w + cg1.w);
        #pragma unroll
        for (int off = 32; off; off >>= 1) p += __shfl_xor(p, off, 64);
        if (lane == 0) z_ext[b * TDIM + t] = p;
    }
}

// ---------------------------------------------------------------------------
// out kernel: softmax over k, extended softmax -> beta; c_t = alpha @ att; blend.
// ---------------------------------------------------------------------------
__global__ __launch_bounds__(256) void out_kernel(const float* __restrict__ z_t,
                                                  const float* __restrict__ z_ext,
                                                  const float* __restrict__ att,
                                                  const float* __restrict__ sen,
                                                  float* __restrict__ out_chat,
                                                  float* __restrict__ out_alpha,
                                                  float* __restrict__ out_beta) {
    __shared__ float alpha_s[KDIM];
    __shared__ float red[8];

    const int t = blockIdx.x;
    const int b = blockIdx.y;
    const int tid = threadIdx.x;

    const float* zrow = z_t + ((size_t)b * TDIM + t) * KDIM;
    float z = (tid < KDIM) ? zrow[tid] : -INFINITY;

    float m = z;
    #pragma unroll
    for (int off = 32; off; off >>= 1) m = fmaxf(m, __shfl_xor(m, off, 64));
    if ((tid & 63) == 0) red[tid >> 6] = m;
    __syncthreads();
    m = fmaxf(fmaxf(red[0], red[1]), fmaxf(red[2], red[3]));

    float e = (tid < KDIM) ? __expf(z - m) : 0.0f;
    float s = e;
    #pragma unroll
    for (int off = 32; off; off >>= 1) s += __shfl_xor(s, off, 64);
    if ((tid & 63) == 0) red[4 + (tid >> 6)] = s;
    __syncthreads();
    float S = red[4] + red[5] + red[6] + red[7];

    float alpha = e / S;
    if (tid < KDIM) {
        alpha_s[tid] = alpha;
        out_alpha[((size_t)b * TDIM + t) * KDIM + tid] = alpha;
    }

    float se = z_ext[b * TDIM + t];
    float m2 = fmaxf(m, se);
    float eext = __expf(se - m2);
    float S2 = S * __expf(m - m2) + eext;
    float beta = eext / S2;
    if (tid == 0) out_beta[b * TDIM + t] = beta;
    __syncthreads();

    const float* attb = att + (size_t)b * KDIM * HDIM;
    float acc0 = 0.f, acc1 = 0.f;
    #pragma unroll 4
    for (int k = 0; k < KDIM; ++k) {
        float a = alpha_s[k];
        acc0 += a * attb[(size_t)k * HDIM + tid];
        acc1 += a * attb[(size_t)k * HDIM + tid + 256];
    }
    const float* srow = sen + ((size_t)b * TDIM + t) * HDIM;
    float om = 1.0f - beta;
    size_t o = ((size_t)b * TDIM + t) * HDIM;
    out_chat[o + tid]       = beta * srow[tid]       + om * acc0;
    out_chat[o + tid + 256] = beta * srow[tid + 256] + om * acc1;
}

// ---------------------------------------------------------------------------
extern "C" void kernel_launch(void* const* d_in, const int* in_sizes, int n_in,
                              void* d_out, int out_size, void* d_ws, size_t ws_size,
                              hipStream_t stream) {
    const float* att = (const float*)d_in[0];
    const float* hid = (const float*)d_in[1];
    const float* sen = (const float*)d_in[2];
    const float* Wv  = (const float*)d_in[3];
    const float* Wg  = (const float*)d_in[4];
    const float* Ws  = (const float*)d_in[5];
    const float* wh  = (const float*)d_in[6];

    float* out = (float*)d_out;
    float* out_chat  = out;
    float* out_alpha = out + 524288;
    float* out_beta  = out + 524288 + 200704;

    char* wsb = (char*)d_ws;
    const size_t C_BYTES  = (size_t)MROWS * 512 * 4;   // 17,039,360
    const size_t ZT_BYTES = 200704 * 4;                // 802,816
    const size_t ZE_BYTES = 4096;
    const size_t AH_BYTES = (size_t)MROWS * 512 * 2;   // 8,519,680
    const size_t BT_BYTES = (size_t)3 * 512 * 512 * 2; // 1,572,864
    const size_t need = C_BYTES + ZT_BYTES + ZE_BYTES + 2 * AH_BYTES + 2 * BT_BYTES;

    float* C  = (float*)wsb;
    float* cv = C;
    float* cg = C + 6272 * 512;
    float* cs = C + 7296 * 512;
    float* zt = (float*)(wsb + C_BYTES);
    float* ze = (float*)(wsb + C_BYTES + ZT_BYTES);

    if (ws_size >= need) {
        __hip_bfloat16* ahi  = (__hip_bfloat16*)(wsb + C_BYTES + ZT_BYTES + ZE_BYTES);
        __hip_bfloat16* alo  = ahi + (size_t)MROWS * 512;
        __hip_bfloat16* bthi = alo + (size_t)MROWS * 512;
        __hip_bfloat16* btlo = bthi + (size_t)3 * 512 * 512;

        convA<<<4160, 256, 0, stream>>>(att, hid, sen, ahi, alo);
        convB<<<dim3(8, 8, 3), 256, 0, stream>>>(Wv, Wg, Ws, bthi, btlo);
        gemm_bf16x3<<<dim3(130, 4), 256, 0, stream>>>(ahi, alo, bthi, btlo, C);
    } else {
        gemm_f32<<<dim3(98, 8), 256, 0, stream>>>(att, Wv, cv);
        gemm_f32<<<dim3(16, 8), 256, 0, stream>>>(hid, Wg, cg);
        gemm_f32<<<dim3(16, 8), 256, 0, stream>>>(sen, Ws, cs);
    }

    z_kernel<<<dim3(BATCH, 4, 4), 512, 0, stream>>>(cv, cg, cs, wh, zt, ze);

    out_kernel<<<dim3(TDIM, BATCH), 256, 0, stream>>>(zt, ze, att, sen,
                                                      out_chat, out_alpha, out_beta);
}

// Round 3
// 164.902 us; speedup vs baseline: 1.5869x; 1.0066x over previous
//
#include <hip/hip_runtime.h>
#include <hip/hip_bf16.h>
#include <math.h>

#define HDIM 512
#define ADIM 512
#define BATCH 32
#define TDIM 32
#define KDIM 196
#define MROWS 8320            // 6272 (att) + 1024 (hid) + 1024 (sen)

typedef short short8 __attribute__((ext_vector_type(8)));
typedef float floatx4 __attribute__((ext_vector_type(4)));

// ---------------------------------------------------------------------------
// async global->LDS 16B copy (global_load_lds_dwordx4)
// ---------------------------------------------------------------------------
__device__ __forceinline__ void gl_lds16(const __hip_bfloat16* g, __hip_bfloat16* l) {
    __builtin_amdgcn_global_load_lds(
        (const __attribute__((address_space(1))) unsigned int*)(const void*)g,
        (__attribute__((address_space(3))) unsigned int*)(void*)l, 16, 0, 0);
}

// ---------------------------------------------------------------------------
// convA: fp32 rows of att|hid|sen -> bf16 hi/lo arrays [8320 x 512]
// ---------------------------------------------------------------------------
__global__ __launch_bounds__(256) void convA(const float* __restrict__ att,
                                             const float* __restrict__ hid,
                                             const float* __restrict__ sen,
                                             __hip_bfloat16* __restrict__ ahi,
                                             __hip_bfloat16* __restrict__ alo) {
    const int idx = blockIdx.x * 256 + threadIdx.x;
    const int row = idx >> 7;                  // 128 float4 per row
    float4 v;
    if (row < 6272)      v = ((const float4*)att)[idx];
    else if (row < 7296) v = ((const float4*)hid)[idx - 6272 * 128];
    else                 v = ((const float4*)sen)[idx - 7296 * 128];
    float x[4] = {v.x, v.y, v.z, v.w};
    union { __hip_bfloat16 b[4]; uint2 u; } H, L;
    #pragma unroll
    for (int i = 0; i < 4; ++i) {
        H.b[i] = __float2bfloat16(x[i]);
        L.b[i] = __float2bfloat16(x[i] - __bfloat162float(H.b[i]));
    }
    ((uint2*)ahi)[idx] = H.u;
    ((uint2*)alo)[idx] = L.u;
}

// ---------------------------------------------------------------------------
// convB: W[k][n] fp32 -> transposed bf16 hi/lo [3][n=512][k=512]
// ---------------------------------------------------------------------------
__global__ __launch_bounds__(256) void convB(const float* __restrict__ Wv,
                                             const float* __restrict__ Wg,
                                             const float* __restrict__ Ws,
                                             __hip_bfloat16* __restrict__ bthi,
                                             __hip_bfloat16* __restrict__ btlo) {
    __shared__ float tile[64][65];
    const int tid = threadIdx.x;
    const float* src = blockIdx.z == 0 ? Wv : (blockIdx.z == 1 ? Wg : Ws);
    const int k0 = blockIdx.x * 64, n0 = blockIdx.y * 64;
    #pragma unroll
    for (int i = 0; i < 16; ++i) {
        int k = (tid >> 6) * 16 + i;
        int n = tid & 63;
        tile[k][n] = src[(size_t)(k0 + k) * 512 + n0 + n];
    }
    __syncthreads();
    const size_t obase = (size_t)blockIdx.z * 262144;
    #pragma unroll
    for (int i = 0; i < 16; ++i) {
        int n = (tid >> 6) * 16 + i;
        int k = tid & 63;
        float x = tile[k][n];
        __hip_bfloat16 h = __float2bfloat16(x);
        __hip_bfloat16 l = __float2bfloat16(x - __bfloat162float(h));
        size_t o = obase + (size_t)(n0 + n) * 512 + k0 + k;
        bthi[o] = h;
        btlo[o] = l;
    }
}

// ---------------------------------------------------------------------------
// split-bf16 MFMA GEMM (bf16x3): C[8320 x 512] = [att|hid|sen] @ [Wv|Wg|Ws]
// ---------------------------------------------------------------------------
__global__ __launch_bounds__(256) void gemm_bf16x3(
        const __hip_bfloat16* __restrict__ Ahi, const __hip_bfloat16* __restrict__ Alo,
        const __hip_bfloat16* __restrict__ Bthi, const __hip_bfloat16* __restrict__ Btlo,
        float* __restrict__ C) {
    __shared__ __hip_bfloat16 smem[12288];

    const int tid  = threadIdx.x;
    const int lane = tid & 63;
    const int wave = tid >> 6;
    const int wm = wave >> 1;
    const int wn = wave & 1;
    const int row0 = blockIdx.x * 64;
    const int col0 = blockIdx.y * 128;
    const int seg = (row0 < 6272) ? 0 : ((row0 < 7296) ? 1 : 2);
    const __hip_bfloat16* Bh = Bthi + (size_t)seg * 262144;
    const __hip_bfloat16* Bl = Btlo + (size_t)seg * 262144;

    floatx4 acc[2][4];
    #pragma unroll
    for (int i = 0; i < 2; ++i)
        #pragma unroll
        for (int j = 0; j < 4; ++j)
            acc[i][j] = (floatx4){0.f, 0.f, 0.f, 0.f};

    const int kq8 = (lane >> 4) << 3;

    for (int k0 = 0; k0 < 512; k0 += 32) {
        #pragma unroll
        for (int s = 0; s < 6; ++s) {
            int u = tid + (s << 8);
            __hip_bfloat16* ldst = smem + u * 8;
            const __hip_bfloat16* gsrc;
            if (u < 256)        gsrc = Ahi + (size_t)(row0 + (u >> 2)) * 512 + k0 + ((u & 3) << 3);
            else if (u < 512)   { int v = u - 256;  gsrc = Alo + (size_t)(row0 + (v >> 2)) * 512 + k0 + ((v & 3) << 3); }
            else if (u < 1024)  { int v = u - 512;  gsrc = Bh  + (size_t)(col0 + (v >> 2)) * 512 + k0 + ((v & 3) << 3); }
            else                { int v = u - 1024; gsrc = Bl  + (size_t)(col0 + (v >> 2)) * 512 + k0 + ((v & 3) << 3); }
            gl_lds16(gsrc, ldst);
        }
        asm volatile("s_waitcnt vmcnt(0)" ::: "memory");
        __syncthreads();

        short8 a_hi[2], a_lo[2], b_hi[4], b_lo[4];
        #pragma unroll
        for (int i = 0; i < 2; ++i) {
            int m = wm * 32 + i * 16 + (lane & 15);
            a_hi[i] = *(const short8*)(smem + m * 32 + kq8);
            a_lo[i] = *(const short8*)(smem + 2048 + m * 32 + kq8);
        }
        #pragma unroll
        for (int j = 0; j < 4; ++j) {
            int n = wn * 64 + j * 16 + (lane & 15);
            b_hi[j] = *(const short8*)(smem + 4096 + n * 32 + kq8);
            b_lo[j] = *(const short8*)(smem + 8192 + n * 32 + kq8);
        }

        #pragma unroll
        for (int i = 0; i < 2; ++i)
            #pragma unroll
            for (int j = 0; j < 4; ++j) {
                acc[i][j] = __builtin_amdgcn_mfma_f32_16x16x32_bf16(a_hi[i], b_hi[j], acc[i][j], 0, 0, 0);
                acc[i][j] = __builtin_amdgcn_mfma_f32_16x16x32_bf16(a_hi[i], b_lo[j], acc[i][j], 0, 0, 0);
                acc[i][j] = __builtin_amdgcn_mfma_f32_16x16x32_bf16(a_lo[i], b_hi[j], acc[i][j], 0, 0, 0);
            }
        __syncthreads();
    }

    #pragma unroll
    for (int i = 0; i < 2; ++i) {
        #pragma unroll
        for (int r = 0; r < 4; ++r) {
            int row = row0 + wm * 32 + i * 16 + ((lane >> 4) << 2) + r;
            float* cp = C + (size_t)row * 512 + col0 + wn * 64 + (lane & 15);
            #pragma unroll
            for (int j = 0; j < 4; ++j) cp[j * 16] = acc[i][j][r];
        }
    }
}

// ---------------------------------------------------------------------------
// z kernel v2 — no cross-lane reduction. Lane owns one (t,k) pair.
// Block 256 thr: k_local = tid>>5 (8 k), t = tid&31 (32 t). Grid (25 kb, 32 b).
// Inner: acc += wh[a] * tanh(cv'+cg') with cv',cg' pre-scaled by 2*log2(e),
// tanh(u) = 1 - 2*rcp(exp2(u')+1): 4 VALU + 2 trans per eval, zero shuffles.
// Sentinel z_ext: last kb block, wave 2, lanes 0..31 (t = lane), uses cs.
// ---------------------------------------------------------------------------
#define ZSC 2.885390081777927f   // 2*log2(e)

__global__ __launch_bounds__(256) void z_kernel(const float* __restrict__ cv,
                                                const float* __restrict__ cg,
                                                const float* __restrict__ cs,
                                                const float* __restrict__ wh,
                                                float* __restrict__ z_t,
                                                float* __restrict__ z_ext) {
    __shared__ float cvs[8][132];    // +4 pad: 16B-aligned rows
    __shared__ float cgs[32][132];
    __shared__ float css[32][132];
    __shared__ float whs[132];

    const int kb   = blockIdx.x;         // 0..24
    const int b    = blockIdx.y;
    const int tid  = threadIdx.x;
    const int wave = tid >> 6;
    const int lane = tid & 63;
    const int t       = tid & 31;
    const int k_local = tid >> 5;        // 0..7
    const int k       = kb * 8 + k_local;
    const bool do_z = (k < KDIM);
    const bool do_s = (kb == 24) && (wave == 2) && (lane < 32);
    const bool last = (kb == 24);

    const int r_st = tid >> 5;           // staging row for cvs (0..7)
    const int q_st = tid & 31;           // staging quad

    float acc = 0.f, acc2 = 0.f, acc_s = 0.f, acc_s2 = 0.f;

    for (int c = 0; c < 4; ++c) {
        const int a0 = c * 128;
        __syncthreads();                 // previous chunk consumed
        // ---- stage cv (8 rows x 128) ----
        {
            int kr = kb * 8 + r_st;
            if (kr < KDIM) {
                float4 v = *(const float4*)(cv + ((size_t)b * KDIM + kr) * ADIM + a0 + 4 * q_st);
                *(float4*)&cvs[r_st][4 * q_st] = make_float4(v.x * ZSC, v.y * ZSC, v.z * ZSC, v.w * ZSC);
            }
        }
        // ---- stage cg (32 rows x 128): 4 float4/thread ----
        #pragma unroll
        for (int s = 0; s < 4; ++s) {
            int idx = tid + s * 256;
            int rr = idx >> 5, qq = idx & 31;
            float4 v = *(const float4*)(cg + ((size_t)b * TDIM + rr) * ADIM + a0 + 4 * qq);
            *(float4*)&cgs[rr][4 * qq] = make_float4(v.x * ZSC, v.y * ZSC, v.z * ZSC, v.w * ZSC);
        }
        // ---- stage cs (only last kb block needs it) ----
        if (last) {
            #pragma unroll
            for (int s = 0; s < 4; ++s) {
                int idx = tid + s * 256;
                int rr = idx >> 5, qq = idx & 31;
                float4 v = *(const float4*)(cs + ((size_t)b * TDIM + rr) * ADIM + a0 + 4 * qq);
                *(float4*)&css[rr][4 * qq] = make_float4(v.x * ZSC, v.y * ZSC, v.z * ZSC, v.w * ZSC);
            }
        }
        // ---- stage wh ----
        if (tid < 32)
            *(float4*)&whs[4 * tid] = *(const float4*)(wh + a0 + 4 * tid);
        __syncthreads();

        // ---- compute: 32 quads ----
        if (do_z) {
            #pragma unroll 16
            for (int q = 0; q < 32; ++q) {
                float4 v  = *(const float4*)&cvs[k_local][4 * q];
                float4 g  = *(const float4*)&cgs[t][4 * q];
                float4 w4 = *(const float4*)&whs[4 * q];
                float e0 = __builtin_amdgcn_exp2f(v.x + g.x);
                float e1 = __builtin_amdgcn_exp2f(v.y + g.y);
                float e2 = __builtin_amdgcn_exp2f(v.z + g.z);
                float e3 = __builtin_amdgcn_exp2f(v.w + g.w);
                float r0 = __builtin_amdgcn_rcpf(e0 + 1.0f);
                float r1 = __builtin_amdgcn_rcpf(e1 + 1.0f);
                float r2 = __builtin_amdgcn_rcpf(e2 + 1.0f);
                float r3 = __builtin_amdgcn_rcpf(e3 + 1.0f);
                acc  = fmaf(w4.x, fmaf(-2.0f, r0, 1.0f), acc);
                acc2 = fmaf(w4.y, fmaf(-2.0f, r1, 1.0f), acc2);
                acc  = fmaf(w4.z, fmaf(-2.0f, r2, 1.0f), acc);
                acc2 = fmaf(w4.w, fmaf(-2.0f, r3, 1.0f), acc2);
            }
        }
        if (do_s) {
            #pragma unroll 16
            for (int q = 0; q < 32; ++q) {
                float4 v  = *(const float4*)&css[lane][4 * q];
                float4 g  = *(const float4*)&cgs[lane][4 * q];
                float4 w4 = *(const float4*)&whs[4 * q];
                float e0 = __builtin_amdgcn_exp2f(v.x + g.x);
                float e1 = __builtin_amdgcn_exp2f(v.y + g.y);
                float e2 = __builtin_amdgcn_exp2f(v.z + g.z);
                float e3 = __builtin_amdgcn_exp2f(v.w + g.w);
                float r0 = __builtin_amdgcn_rcpf(e0 + 1.0f);
                float r1 = __builtin_amdgcn_rcpf(e1 + 1.0f);
                float r2 = __builtin_amdgcn_rcpf(e2 + 1.0f);
                float r3 = __builtin_amdgcn_rcpf(e3 + 1.0f);
                acc_s  = fmaf(w4.x, fmaf(-2.0f, r0, 1.0f), acc_s);
                acc_s2 = fmaf(w4.y, fmaf(-2.0f, r1, 1.0f), acc_s2);
                acc_s  = fmaf(w4.z, fmaf(-2.0f, r2, 1.0f), acc_s);
                acc_s2 = fmaf(w4.w, fmaf(-2.0f, r3, 1.0f), acc_s2);
            }
        }
    }

    if (do_z) z_t[((size_t)b * TDIM + t) * KDIM + k] = acc + acc2;
    if (do_s) z_ext[b * TDIM + lane] = acc_s + acc_s2;
}

// ---------------------------------------------------------------------------
// out kernel v2: block = (b, group of 4 t); wave w handles t's softmax;
// shared k-loop applies all 4 alphas per att element (att traffic / 4).
// ---------------------------------------------------------------------------
__global__ __launch_bounds__(256) void out_kernel(const float* __restrict__ z_t,
                                                  const float* __restrict__ z_ext,
                                                  const float* __restrict__ att,
                                                  const float* __restrict__ sen,
                                                  float* __restrict__ out_chat,
                                                  float* __restrict__ out_alpha,
                                                  float* __restrict__ out_beta) {
    __shared__ float alpha_s[4][200];
    __shared__ float beta_s[4];

    const int tg = blockIdx.x;      // 0..7
    const int b  = blockIdx.y;
    const int tid  = threadIdx.x;
    const int wave = tid >> 6;
    const int lane = tid & 63;
    const int t = tg * 4 + wave;

    const float* zrow = z_t + ((size_t)b * TDIM + t) * KDIM;
    float z0 = zrow[lane];
    float z1 = zrow[lane + 64];
    float z2 = zrow[lane + 128];
    float z3 = (lane < 4) ? zrow[lane + 192] : -INFINITY;

    float m = fmaxf(fmaxf(z0, z1), fmaxf(z2, z3));
    #pragma unroll
    for (int off = 32; off; off >>= 1) m = fmaxf(m, __shfl_xor(m, off, 64));

    float e0 = __expf(z0 - m), e1 = __expf(z1 - m);
    float e2 = __expf(z2 - m), e3 = (lane < 4) ? __expf(z3 - m) : 0.0f;
    float s = e0 + e1 + e2 + e3;
    #pragma unroll
    for (int off = 32; off; off >>= 1) s += __shfl_xor(s, off, 64);

    float invS = 1.0f / s;
    float a0 = e0 * invS, a1 = e1 * invS, a2 = e2 * invS, a3 = e3 * invS;

    float* arow = out_alpha + ((size_t)b * TDIM + t) * KDIM;
    alpha_s[wave][lane] = a0;        arow[lane] = a0;
    alpha_s[wave][lane + 64] = a1;   arow[lane + 64] = a1;
    alpha_s[wave][lane + 128] = a2;  arow[lane + 128] = a2;
    if (lane < 4) { alpha_s[wave][lane + 192] = a3; arow[lane + 192] = a3; }

    if (lane == 0) {
        float se = z_ext[b * TDIM + t];
        float m2 = fmaxf(m, se);
        float eext = __expf(se - m2);
        float S2 = s * __expf(m - m2) + eext;
        float beta = eext / S2;
        beta_s[wave] = beta;
        out_beta[b * TDIM + t] = beta;
    }
    __syncthreads();

    // c_t for 4 t's: thread covers h = tid and tid+256
    const float* attb = att + (size_t)b * KDIM * HDIM;
    float acc[4][2] = {};
    #pragma unroll 4
    for (int k = 0; k < KDIM; ++k) {
        float av0 = attb[(size_t)k * HDIM + tid];
        float av1 = attb[(size_t)k * HDIM + tid + 256];
        #pragma unroll
        for (int w = 0; w < 4; ++w) {
            float a = alpha_s[w][k];
            acc[w][0] = fmaf(a, av0, acc[w][0]);
            acc[w][1] = fmaf(a, av1, acc[w][1]);
        }
    }

    #pragma unroll
    for (int w = 0; w < 4; ++w) {
        int tt = tg * 4 + w;
        float beta = beta_s[w];
        float om = 1.0f - beta;
        size_t o = ((size_t)b * TDIM + tt) * HDIM;
        out_chat[o + tid]       = fmaf(beta, sen[o + tid],       om * acc[w][0]);
        out_chat[o + tid + 256] = fmaf(beta, sen[o + tid + 256], om * acc[w][1]);
    }
}

// ---------------------------------------------------------------------------
// fallback fp32 tiled GEMM (only if workspace too small for bf16 path)
// ---------------------------------------------------------------------------
__global__ __launch_bounds__(256) void gemm_f32(const float* __restrict__ Amat,
                                                const float* __restrict__ Bmat,
                                                float* __restrict__ Cmat) {
    __shared__ float As[16][64 + 4];
    __shared__ float Bs[16][64];
    const int tid = threadIdx.x;
    const int tx = tid & 15;
    const int ty = tid >> 4;
    const int row0 = blockIdx.x * 64;
    const int col0 = blockIdx.y * 64;
    float acc[4][4] = {};
    for (int k0 = 0; k0 < HDIM; k0 += 16) {
        #pragma unroll
        for (int i = 0; i < 4; ++i) {
            int idx = tid + i * 256;
            As[idx & 15][idx >> 4] = Amat[(size_t)(row0 + (idx >> 4)) * HDIM + k0 + (idx & 15)];
        }
        #pragma unroll
        for (int i = 0; i < 4; ++i) {
            int idx = tid + i * 256;
            Bs[idx >> 6][idx & 63] = Bmat[(size_t)(k0 + (idx >> 6)) * ADIM + col0 + (idx & 63)];
        }
        __syncthreads();
        #pragma unroll
        for (int k = 0; k < 16; ++k) {
            float4 a4 = *(const float4*)&As[k][ty * 4];
            float4 b4 = *(const float4*)&Bs[k][tx * 4];
            float a[4] = {a4.x, a4.y, a4.z, a4.w};
            float b[4] = {b4.x, b4.y, b4.z, b4.w};
            #pragma unroll
            for (int i = 0; i < 4; ++i)
                #pragma unroll
                for (int j = 0; j < 4; ++j)
                    acc[i][j] += a[i] * b[j];
        }
        __syncthreads();
    }
    #pragma unroll
    for (int i = 0; i < 4; ++i) {
        size_t r = (size_t)(row0 + ty * 4 + i) * ADIM + col0 + tx * 4;
        #pragma unroll
        for (int j = 0; j < 4; ++j) Cmat[r + j] = acc[i][j];
    }
}

// ---------------------------------------------------------------------------
extern "C" void kernel_launch(void* const* d_in, const int* in_sizes, int n_in,
                              void* d_out, int out_size, void* d_ws, size_t ws_size,
                              hipStream_t stream) {
    const float* att = (const float*)d_in[0];
    const float* hid = (const float*)d_in[1];
    const float* sen = (const float*)d_in[2];
    const float* Wv  = (const float*)d_in[3];
    const float* Wg  = (const float*)d_in[4];
    const float* Ws  = (const float*)d_in[5];
    const float* wh  = (const float*)d_in[6];

    float* out = (float*)d_out;
    float* out_chat  = out;
    float* out_alpha = out + 524288;
    float* out_beta  = out + 524288 + 200704;

    char* wsb = (char*)d_ws;
    const size_t C_BYTES  = (size_t)MROWS * 512 * 4;
    const size_t ZT_BYTES = 200704 * 4;
    const size_t ZE_BYTES = 4096;
    const size_t AH_BYTES = (size_t)MROWS * 512 * 2;
    const size_t BT_BYTES = (size_t)3 * 512 * 512 * 2;
    const size_t need = C_BYTES + ZT_BYTES + ZE_BYTES + 2 * AH_BYTES + 2 * BT_BYTES;

    float* C  = (float*)wsb;
    float* cv = C;
    float* cg = C + 6272 * 512;
    float* cs = C + 7296 * 512;
    float* zt = (float*)(wsb + C_BYTES);
    float* ze = (float*)(wsb + C_BYTES + ZT_BYTES);

    if (ws_size >= need) {
        __hip_bfloat16* ahi  = (__hip_bfloat16*)(wsb + C_BYTES + ZT_BYTES + ZE_BYTES);
        __hip_bfloat16* alo  = ahi + (size_t)MROWS * 512;
        __hip_bfloat16* bthi = alo + (size_t)MROWS * 512;
        __hip_bfloat16* btlo = bthi + (size_t)3 * 512 * 512;

        convA<<<4160, 256, 0, stream>>>(att, hid, sen, ahi, alo);
        convB<<<dim3(8, 8, 3), 256, 0, stream>>>(Wv, Wg, Ws, bthi, btlo);
        gemm_bf16x3<<<dim3(130, 4), 256, 0, stream>>>(ahi, alo, bthi, btlo, C);
    } else {
        gemm_f32<<<dim3(98, 8), 256, 0, stream>>>(att, Wv, cv);
        gemm_f32<<<dim3(16, 8), 256, 0, stream>>>(hid, Wg, cg);
        gemm_f32<<<dim3(16, 8), 256, 0, stream>>>(sen, Ws, cs);
    }

    z_kernel<<<dim3(25, 32), 256, 0, stream>>>(cv, cg, cs, wh, zt, ze);

    out_kernel<<<dim3(8, 32), 256, 0, stream>>>(zt, ze, att, sen,
                                                out_chat, out_alpha, out_beta);
}